// Round 13
// baseline (336.986 us; speedup 1.0000x reference)
//
#include <hip/hip_runtime.h>
#include <cstdint>

// MambaBlock: out = (silu(x@in_w[:1024]^T+b0) * silu(x@in_w[1024:]^T+b1)) @ out_w^T + out_b
// M = 32768, K = 1024. dt_w/dt_b/A/Dp are dead inputs.
//
// Round 13: B (weights, L2-resident: W1 4MB / W2 2MB per-XCD) is read DIRECTLY
// from global into a double register set (P/Q, prefetch 1 tile ahead), deleting
// B from LDS. LDS pipe load drops 96+32 -> 64+16 KB/K-tile (A-only, 4 bufs x
// 16 KB, depth-2); B rides the parallel VMEM pipe. vmcnt ledger per tile k:
// entry {vmcnt(2); barrier} retires As(k)+Bf(k), leaves As(k+1); body issues
// [Bf(k+1) -> other set, As(k+2) -> buf (k+2)%4, compute(k)]. Never drains.
// Occupancy is register-pinned at 2 waves/SIMD (unified 512-reg/SIMD file,
// 128-float acc): r12 proved LDS cuts don't add blocks; this round attacks
// the serialized LDS pipe instead. Arch VGPR budget ~120 (+acc 128 = 248<=256).
// Core otherwise r6/r11-verified: 256x256 tile, BK=32, 8 waves 2Mx4N, 32x32x16
// MFMA, A swizzle key2(row)=((row>>1)^(row>>4))&3 (0 conflicts), setprio,
// bijective XCD swizzle, shuffle-free paired-silu epilogue (blk32 W1).

typedef __bf16 bf16x8 __attribute__((ext_vector_type(8)));
typedef float f32x16 __attribute__((ext_vector_type(16)));

#define KD 1024
#define ABUF_ELEMS 8192  // 256 rows x 32 K elems (16 KiB) per A buffer

__device__ __forceinline__ void gload_lds16(const void* g, void* lds_u) {
  __builtin_amdgcn_global_load_lds(
      (__attribute__((address_space(1))) void*)(uintptr_t)g,
      (__attribute__((address_space(3))) void*)(uint32_t)(uintptr_t)lds_u,
      16, 0, 0);
}

#define WAITB(N) do { \
  asm volatile("s_waitcnt vmcnt(" #N ")" ::: "memory"); \
  asm volatile("s_barrier" ::: "memory"); } while (0)

// ---------------- merged cast kernel (single launch) ----------------
// blocks [0, 16384): x -> xb; [16384, 17408): in_w -> w1b (blk32 interleave);
// [17408, 17920): out_w -> w2b
__global__ void cast_all(const float* __restrict__ x, __bf16* __restrict__ xb,
                         const float* __restrict__ in_w, __bf16* __restrict__ w1b,
                         const float* __restrict__ out_w, __bf16* __restrict__ w2b) {
  const int b = blockIdx.x;
  if (b < 16384) {
    int i = b * 256 + threadIdx.x;  // < 4194304 = 33554432/8
    const float4* p = (const float4*)x;
    float4 v0 = p[2 * i];
    float4 v1 = p[2 * i + 1];
    bf16x8 o;
    o[0] = (__bf16)v0.x; o[1] = (__bf16)v0.y; o[2] = (__bf16)v0.z; o[3] = (__bf16)v0.w;
    o[4] = (__bf16)v1.x; o[5] = (__bf16)v1.y; o[6] = (__bf16)v1.z; o[7] = (__bf16)v1.w;
    ((bf16x8*)xb)[i] = o;
  } else if (b < 17408) {
    // W1'' 32-row block interleave: out-row r, blk=r>>5, t=r&31:
    //   src row = (blk&1)*1024 + (blk>>1)*32 + t
    int i = (b - 16384) * 256 + threadIdx.x;  // 2048*128 threads
    int orow = i >> 7;
    int chunk = i & 127;
    int bb = orow >> 5, t = orow & 31;
    int srow = (bb & 1) * 1024 + (bb >> 1) * 32 + t;
    const float4* p = (const float4*)(in_w + ((size_t)srow << 10) + (chunk << 3));
    float4 v0 = p[0], v1 = p[1];
    bf16x8 o;
    o[0] = (__bf16)v0.x; o[1] = (__bf16)v0.y; o[2] = (__bf16)v0.z; o[3] = (__bf16)v0.w;
    o[4] = (__bf16)v1.x; o[5] = (__bf16)v1.y; o[6] = (__bf16)v1.z; o[7] = (__bf16)v1.w;
    *(bf16x8*)(w1b + ((size_t)orow << 10) + (chunk << 3)) = o;
  } else {
    int i = (b - 17408) * 256 + threadIdx.x;  // < 131072 = 1048576/8
    const float4* p = (const float4*)out_w;
    float4 v0 = p[2 * i];
    float4 v1 = p[2 * i + 1];
    bf16x8 o;
    o[0] = (__bf16)v0.x; o[1] = (__bf16)v0.y; o[2] = (__bf16)v0.z; o[3] = (__bf16)v0.w;
    o[4] = (__bf16)v1.x; o[5] = (__bf16)v1.y; o[6] = (__bf16)v1.z; o[7] = (__bf16)v1.w;
    ((bf16x8*)w2b)[i] = o;
  }
}

// ---------------- GEMM core ----------------
// Stage one 256x32 A K-tile into buffer BUF. 2 gloads per wave.
template <int BUF>
__device__ __forceinline__ void stageA(const __bf16*& pa, __bf16* smw) {
  __bf16* d = smw + BUF * ABUF_ELEMS;
  gload_lds16(pa, d);
  gload_lds16(pa + 128 * KD, d + 4096);
  pa += 32;
}

// B fragments for one K-tile direct from global (logical layout, no swizzle):
// SET[j][s] = 8 bf16 at row (n0 + wc*64 + j*32 + c31), k = k0 + s*16 + hi*8.
#define LDB(SET) do { \
  SET[0][0] = *(const bf16x8*)(pb0); \
  SET[0][1] = *(const bf16x8*)(pb0 + 16); \
  SET[1][0] = *(const bf16x8*)(pb1); \
  SET[1][1] = *(const bf16x8*)(pb1 + 16); \
  pb0 += 32; pb1 += 32; \
} while (0)

// 32x32x16 MFMA on A from LDS buf + B from register SET. A chunk swizzle:
// phys = logical ^ key2(row); i-parity flips between e0 and e0^16 (r6 math).
#define CTILE(BUF, SET) do { \
  const __bf16* base_ = sm + (BUF) * ABUF_ELEMS; \
  bf16x8 a0[4], a1[4]; \
  _Pragma("unroll") for (int i = 0; i < 4; ++i) { \
    const int e0 = (i & 1) ? o1 : o0; \
    a0[i] = *(const bf16x8*)(base_ + aRow + i * 1024 + e0); \
    a1[i] = *(const bf16x8*)(base_ + aRow + i * 1024 + (e0 ^ 16)); \
  } \
  __builtin_amdgcn_s_setprio(1); \
  _Pragma("unroll") for (int i = 0; i < 4; ++i) \
    _Pragma("unroll") for (int j = 0; j < 2; ++j) \
      acc[i][j] = __builtin_amdgcn_mfma_f32_32x32x16_bf16(a0[i], SET[j][0], acc[i][j], 0, 0, 0); \
  _Pragma("unroll") for (int i = 0; i < 4; ++i) \
    _Pragma("unroll") for (int j = 0; j < 2; ++j) \
      acc[i][j] = __builtin_amdgcn_mfma_f32_32x32x16_bf16(a1[i], SET[j][1], acc[i][j], 0, 0, 0); \
  __builtin_amdgcn_s_setprio(0); \
} while (0)

// Fills acc for the 256x256 tile at (m0, n0). A:[M][1024], B:[Nrows][1024].
__device__ __forceinline__ void gemm_core(const __bf16* __restrict__ A,
                                          const __bf16* __restrict__ B,
                                          __bf16* sm, long m0, long n0,
                                          f32x16 (&acc)[4][2]) {
  const int t = threadIdx.x;
  const int w = t >> 6;
  const int lane = t & 63;
  const int c31 = lane & 31;
  const int hi = lane >> 5;
  const int wr = w >> 2;  // 0..1 (M)
  const int wc = w & 3;   // 0..3 (N)

  // A staging source: lane l covers LDS row w*16+(l>>2), phys slot l&3, which
  // must hold logical chunk (l&3) ^ key2(row); key2 = ((l>>3)&3) ^ (w&3).
  const int l = lane;
  const int stg_row = w * 16 + (l >> 2);
  const int stg_col = ((l & 3) ^ ((l >> 3) & 3) ^ (w & 3)) << 3;
  const __bf16* pa = A + (m0 + stg_row) * KD + stg_col;
  __bf16* smw = sm + w * 512;  // wave-uniform LDS base (1024B per wave-instr)

  // B fragment pointers (advance 32/tile via LDB)
  const __bf16* pb0 = B + (n0 + wc * 64 + c31) * KD + hi * 8;
  const __bf16* pb1 = pb0 + 32 * KD;

  // A fragment read offsets (r6 math). o1 = o0 ^ 16 elems.
  const int key_base = ((c31 >> 1) & 3) ^ ((c31 >> 4) & 1);
  const int o0 = (hi ^ key_base) << 3;
  const int o1 = o0 ^ 16;
  const int aRow = (wr * 128 + c31) * 32;  // + i*1024

  bf16x8 bfP[2][2], bfQ[2][2];

#pragma unroll
  for (int i = 0; i < 4; ++i)
#pragma unroll
    for (int j = 0; j < 2; ++j)
      acc[i][j] = (f32x16){0.f, 0.f, 0.f, 0.f, 0.f, 0.f, 0.f, 0.f,
                           0.f, 0.f, 0.f, 0.f, 0.f, 0.f, 0.f, 0.f};

  // prologue: issue As(0), Bf(0)->P, As(1). Entry-0 vmcnt(2) retires As0+Bf0.
  stageA<0>(pa, smw);
  LDB(bfP);
  stageA<1>(pa, smw);
  WAITB(2);

  // tiles 0..27 (buf k%4, set parity k%2); body: [Bf(k+1); As(k+2); compute]
  for (int it = 0; it < 7; ++it) {
    LDB(bfQ); stageA<2>(pa, smw); CTILE(0, bfP); WAITB(2);
    LDB(bfP); stageA<3>(pa, smw); CTILE(1, bfQ); WAITB(2);
    LDB(bfQ); stageA<0>(pa, smw); CTILE(2, bfP); WAITB(2);
    LDB(bfP); stageA<1>(pa, smw); CTILE(3, bfQ); WAITB(2);
  }
  // tiles 28..31
  LDB(bfQ); stageA<2>(pa, smw); CTILE(0, bfP); WAITB(2);  // k=28; As(30)
  LDB(bfP); stageA<3>(pa, smw); CTILE(1, bfQ); WAITB(2);  // k=29; As(31)
  LDB(bfQ);                      CTILE(2, bfP); WAITB(0); // k=30; Bf(31)
  CTILE(3, bfQ);                                           // k=31
}

// ---------------- GEMM1: Y = X @ W1''^T, paired-silu epilogue -> G bf16 -----
__global__ __launch_bounds__(512, 2)
void gemm1_silu(const __bf16* __restrict__ X, const __bf16* __restrict__ W1i,
                const float* __restrict__ in_b, __bf16* __restrict__ G) {
  __shared__ __bf16 sm[4 * ABUF_ELEMS];  // 64 KiB, A-only
  // XCD-aware bijective swizzle: nwg = 128*8 = 1024, divisible by 8
  const int bid = blockIdx.x;
  const int swz = (bid & 7) * 128 + (bid >> 3);
  const long m0 = (long)(swz >> 3) * 256;
  const long n0 = (long)(swz & 7) * 256;

  f32x16 acc[4][2];
  gemm_core(X, W1i, sm, m0, n0, acc);

  const int lane = threadIdx.x & 63;
  const int w = threadIdx.x >> 6;
  const int wr = w >> 2, wc = w & 3;
  const int c31 = lane & 31;
  const int hi = lane >> 5;

  // G column for this wave's frag pair: even block j=0 (x_val), odd j=1 (res)
  const int gc = ((int)n0 >> 1) + wc * 32 + c31;
  const float bx = in_b[gc];
  const float br = in_b[1024 + gc];

#pragma unroll
  for (int i = 0; i < 4; ++i)
#pragma unroll
    for (int reg = 0; reg < 16; ++reg) {
      const int row = wr * 128 + i * 32 + (reg & 3) + 8 * (reg >> 2) + 4 * hi;
      float xv = acc[i][0][reg] + bx;
      float rs = acc[i][1][reg] + br;
      float e1 = __expf(-xv);
      float e2 = __expf(-rs);
      float g = xv * rs * __builtin_amdgcn_rcpf((1.0f + e1) * (1.0f + e2));
      G[(m0 + row) * 1024 + gc] = (__bf16)g;
    }
}

// ---------------- GEMM2: OUT = G @ W2^T + out_b (fp32) ----------------
__global__ __launch_bounds__(512, 2)
void gemm2_bias(const __bf16* __restrict__ G, const __bf16* __restrict__ W2,
                const float* __restrict__ out_b, float* __restrict__ OUT) {
  __shared__ __bf16 sm[4 * ABUF_ELEMS];  // 64 KiB, A-only
  // nwg = 128*4 = 512, divisible by 8
  const int bid = blockIdx.x;
  const int swz = (bid & 7) * 64 + (bid >> 3);
  const long m0 = (long)(swz >> 2) * 256;
  const long n0 = (long)(swz & 3) * 256;

  f32x16 acc[4][2];
  gemm_core(G, W2, sm, m0, n0, acc);

  const int lane = threadIdx.x & 63;
  const int w = threadIdx.x >> 6;
  const int wr = w >> 2, wc = w & 3;
  const int c31 = lane & 31;
  const int hi = lane >> 5;

  float ob[2];
#pragma unroll
  for (int j = 0; j < 2; ++j)
    ob[j] = out_b[(int)n0 + wc * 64 + j * 32 + c31];
#pragma unroll
  for (int i = 0; i < 4; ++i)
#pragma unroll
    for (int j = 0; j < 2; ++j)
#pragma unroll
      for (int reg = 0; reg < 16; ++reg) {
        const int row = wr * 128 + i * 32 + (reg & 3) + 8 * (reg >> 2) + 4 * hi;
        const int col = (int)n0 + wc * 64 + j * 32 + c31;
        OUT[(m0 + row) * 1024 + col] = acc[i][j][reg] + ob[j];
      }
}

extern "C" void kernel_launch(void* const* d_in, const int* in_sizes, int n_in,
                              void* d_out, int out_size, void* d_ws, size_t ws_size,
                              hipStream_t stream) {
  const float* x = (const float*)d_in[0];
  const float* in_w = (const float*)d_in[1];
  const float* in_b = (const float*)d_in[2];
  const float* out_w = (const float*)d_in[3];
  const float* out_b = (const float*)d_in[4];
  // d_in[5..8] (dt_w, dt_b, A, Dp) are dead in the reference.

  char* ws = (char*)d_ws;
  __bf16* xb = (__bf16*)(ws);                       // 67108864 B
  __bf16* w1b = (__bf16*)(ws + (size_t)67108864);   //  4194304 B (blk32 interleaved)
  __bf16* w2b = (__bf16*)(ws + (size_t)71303168);   //  2097152 B
  __bf16* gb = (__bf16*)(ws + (size_t)73400320);    // 67108864 B

  cast_all<<<dim3(17920), 256, 0, stream>>>(x, xb, in_w, w1b, out_w, w2b);
  gemm1_silu<<<dim3(1024), 512, 0, stream>>>(xb, w1b, in_b, gb);
  gemm2_bias<<<dim3(512), 512, 0, stream>>>(gb, w2b, out_b, (float*)d_out);
}

// Round 14
// 261.727 us; speedup vs baseline: 1.2875x; 1.2875x over previous
//
#include <hip/hip_runtime.h>
#include <cstdint>

// MambaBlock: out = (silu(x@in_w[:1024]^T+b0) * silu(x@in_w[1024:]^T+b1)) @ out_w^T + out_b
// M = 32768, K = 1024. dt_w/dt_b/A/Dp are dead inputs.
//
// FINAL (round 14) = round 9/11 verified optimum (261.0 us), restored after
// r13's B-direct regression (row-strided per-lane B loads -> 64-way
// uncoalesced L2 scatter per instruction).
// Core: 256x256 tile, BK=32, 512 threads (8 waves, 2Mx4N), triple-buffered LDS
// (96 KiB, 1 block/CU), prefetch depth 2, counted vmcnt(4), 32x32x16 MFMA,
// swizzle key2(row)=((row>>1)^(row>>4))&3 on both stage-source and ds_read
// (measured 0 bank conflicts), setprio around MFMA cluster, bijective XCD
// swizzle, shuffle-free paired-silu epilogue (blk32-interleaved W1),
// single merged cast launch.
// Design-space ledger (all measured): r3/r4 schedule splits null; r5 32x32
// MFMA +17%; r6 swizzle fix +4%; r7 fat tile -> acc spill 25x; r8 bounds
// clamp -> spill; r10 A-cast fusion -71us; r12 LDS-cut neutral (occupancy is
// register-pinned: 104 arch + 128 acc VGPR = 2 waves/SIMD); r13 B-direct -71us.

typedef __bf16 bf16x8 __attribute__((ext_vector_type(8)));
typedef float f32x16 __attribute__((ext_vector_type(16)));

#define KD 1024
#define BUF_ELEMS 16384  // (256*32 A + 256*32 B) elems per buffer

__device__ __forceinline__ void gload_lds16(const void* g, void* lds_u) {
  __builtin_amdgcn_global_load_lds(
      (__attribute__((address_space(1))) void*)(uintptr_t)g,
      (__attribute__((address_space(3))) void*)(uint32_t)(uintptr_t)lds_u,
      16, 0, 0);
}

#define WAITB(N) do { \
  asm volatile("s_waitcnt vmcnt(" #N ")" ::: "memory"); \
  asm volatile("s_barrier" ::: "memory"); } while (0)

// ---------------- merged cast kernel (single launch) ----------------
// blocks [0, 16384): x -> xb (f32->bf16, 8 elems/thread)
// blocks [16384, 17408): in_w -> w1b with 32-row block interleave
// blocks [17408, 17920): out_w -> w2b
__global__ void cast_all(const float* __restrict__ x, __bf16* __restrict__ xb,
                         const float* __restrict__ in_w, __bf16* __restrict__ w1b,
                         const float* __restrict__ out_w, __bf16* __restrict__ w2b) {
  const int b = blockIdx.x;
  if (b < 16384) {
    int i = b * 256 + threadIdx.x;  // < 4194304 = 33554432/8
    const float4* p = (const float4*)x;
    float4 v0 = p[2 * i];
    float4 v1 = p[2 * i + 1];
    bf16x8 o;
    o[0] = (__bf16)v0.x; o[1] = (__bf16)v0.y; o[2] = (__bf16)v0.z; o[3] = (__bf16)v0.w;
    o[4] = (__bf16)v1.x; o[5] = (__bf16)v1.y; o[6] = (__bf16)v1.z; o[7] = (__bf16)v1.w;
    ((bf16x8*)xb)[i] = o;
  } else if (b < 17408) {
    // W1'' 32-row block interleave: out-row r, blk=r>>5, t=r&31:
    //   src row = (blk&1)*1024 + (blk>>1)*32 + t
    int i = (b - 16384) * 256 + threadIdx.x;  // 2048*128 threads
    int orow = i >> 7;
    int chunk = i & 127;
    int bb = orow >> 5, t = orow & 31;
    int srow = (bb & 1) * 1024 + (bb >> 1) * 32 + t;
    const float4* p = (const float4*)(in_w + ((size_t)srow << 10) + (chunk << 3));
    float4 v0 = p[0], v1 = p[1];
    bf16x8 o;
    o[0] = (__bf16)v0.x; o[1] = (__bf16)v0.y; o[2] = (__bf16)v0.z; o[3] = (__bf16)v0.w;
    o[4] = (__bf16)v1.x; o[5] = (__bf16)v1.y; o[6] = (__bf16)v1.z; o[7] = (__bf16)v1.w;
    *(bf16x8*)(w1b + ((size_t)orow << 10) + (chunk << 3)) = o;
  } else {
    int i = (b - 17408) * 256 + threadIdx.x;  // < 131072 = 1048576/8
    const float4* p = (const float4*)out_w;
    float4 v0 = p[2 * i];
    float4 v1 = p[2 * i + 1];
    bf16x8 o;
    o[0] = (__bf16)v0.x; o[1] = (__bf16)v0.y; o[2] = (__bf16)v0.z; o[3] = (__bf16)v0.w;
    o[4] = (__bf16)v1.x; o[5] = (__bf16)v1.y; o[6] = (__bf16)v1.z; o[7] = (__bf16)v1.w;
    ((bf16x8*)w2b)[i] = o;
  }
}

// ---------------- GEMM core ----------------
// Stage one 256x32 K-tile of A and B into buffer BUF. 4 gloads per wave.
template <int BUF>
__device__ __forceinline__ void stage_tile(const __bf16*& pa, const __bf16*& pb,
                                           __bf16* smw) {
  __bf16* d = smw + BUF * BUF_ELEMS;
  gload_lds16(pa, d);
  gload_lds16(pa + 128 * KD, d + 4096);
  gload_lds16(pb, d + 8192);
  gload_lds16(pb + 128 * KD, d + 12288);
  pa += 32;
  pb += 32;
}

// 32x32x16 MFMA. Per K-tile-32: 2 k-slices; 8 A + 4 B b128 reads; 16 MFMA.
// Chunk swizzle: phys = logical ^ key2(row); per frag parity the chunk offset
// alternates between o0 and o1 = o0^16 (key2 flips by 2 when frag idx is odd).
template <int BUF>
__device__ __forceinline__ void compute_tile(const __bf16* sm,
                                             int aRow, int bRow,
                                             int o0, int o1,
                                             f32x16 (&acc)[4][2]) {
  const __bf16* base = sm + BUF * BUF_ELEMS;
  bf16x8 a0[4], a1[4], b0[2], b1[2];
  // j even: ks0 -> o0, ks1 -> o1 ; j odd: swapped
  b0[0] = *(const bf16x8*)(base + bRow + o0);
  b1[0] = *(const bf16x8*)(base + bRow + o1);
  b0[1] = *(const bf16x8*)(base + bRow + 1024 + o1);
  b1[1] = *(const bf16x8*)(base + bRow + 1024 + o0);
#pragma unroll
  for (int i = 0; i < 4; ++i) {
    const int e0 = (i & 1) ? o1 : o0;
    const int e1 = (i & 1) ? o0 : o1;
    a0[i] = *(const bf16x8*)(base + aRow + i * 1024 + e0);
    a1[i] = *(const bf16x8*)(base + aRow + i * 1024 + e1);
  }
  __builtin_amdgcn_s_setprio(1);
#pragma unroll
  for (int i = 0; i < 4; ++i)
#pragma unroll
    for (int j = 0; j < 2; ++j)
      acc[i][j] = __builtin_amdgcn_mfma_f32_32x32x16_bf16(a0[i], b0[j], acc[i][j], 0, 0, 0);
#pragma unroll
  for (int i = 0; i < 4; ++i)
#pragma unroll
    for (int j = 0; j < 2; ++j)
      acc[i][j] = __builtin_amdgcn_mfma_f32_32x32x16_bf16(a1[i], b1[j], acc[i][j], 0, 0, 0);
  __builtin_amdgcn_s_setprio(0);
}

// Fills acc for the 256x256 tile at (m0, n0). A:[M][1024], B:[Nrows][1024].
__device__ __forceinline__ void gemm_core(const __bf16* __restrict__ A,
                                          const __bf16* __restrict__ B,
                                          __bf16* sm, long m0, long n0,
                                          f32x16 (&acc)[4][2]) {
  const int t = threadIdx.x;
  const int w = t >> 6;
  const int lane = t & 63;
  const int c31 = lane & 31;
  const int hi = lane >> 5;
  const int wr = w >> 2;  // 0..1 (M)
  const int wc = w & 3;   // 0..3 (N)

  // staging source: lane l covers LDS row w*16+(l>>2), phys slot l&3, which
  // must hold logical chunk (l&3) ^ key2(row); key2 = ((l>>3)&3) ^ (w&3).
  const int l = lane;
  const int stg_row = w * 16 + (l >> 2);
  const int stg_col = ((l & 3) ^ ((l >> 3) & 3) ^ (w & 3)) << 3;
  const __bf16* pa = A + (m0 + stg_row) * KD + stg_col;
  const __bf16* pb = B + (n0 + stg_row) * KD + stg_col;
  __bf16* smw = sm + w * 512;  // wave-uniform LDS base (1024B per wave-instr)

  // fragment read offsets. key_base = ((c31>>1)&3) ^ ((c31>>4)&1); frag idx
  // parity flips key by 2 (row bit 5 via r>>4). o1 = o0 ^ 16 elems.
  const int key_base = ((c31 >> 1) & 3) ^ ((c31 >> 4) & 1);
  const int o0 = (hi ^ key_base) << 3;
  const int o1 = o0 ^ 16;
  const int aRow = (wr * 128 + c31) * 32;          // + i*1024
  const int bRow = 8192 + (wc * 64 + c31) * 32;    // + j*1024

#pragma unroll
  for (int i = 0; i < 4; ++i)
#pragma unroll
    for (int j = 0; j < 2; ++j)
      acc[i][j] = (f32x16){0.f, 0.f, 0.f, 0.f, 0.f, 0.f, 0.f, 0.f,
                           0.f, 0.f, 0.f, 0.f, 0.f, 0.f, 0.f, 0.f};

  // prologue: stage tiles 0,1
  stage_tile<0>(pa, pb, smw);
  stage_tile<1>(pa, pb, smw);

  // tiles 0..29: compute buf t%3, stage tile t+2 into buf (t+2)%3
  for (int it = 0; it < 10; ++it) {
    WAITB(4); stage_tile<2>(pa, pb, smw);
    compute_tile<0>(sm, aRow, bRow, o0, o1, acc);
    WAITB(4); stage_tile<0>(pa, pb, smw);
    compute_tile<1>(sm, aRow, bRow, o0, o1, acc);
    WAITB(4); stage_tile<1>(pa, pb, smw);
    compute_tile<2>(sm, aRow, bRow, o0, o1, acc);
  }
  // tail: tiles 30 (buf0), 31 (buf1)
  WAITB(4); compute_tile<0>(sm, aRow, bRow, o0, o1, acc);
  WAITB(0); compute_tile<1>(sm, aRow, bRow, o0, o1, acc);
}

// ---------------- GEMM1: Y = X @ W1''^T, paired-silu epilogue -> G bf16 -----
__global__ __launch_bounds__(512, 2)
void gemm1_silu(const __bf16* __restrict__ X, const __bf16* __restrict__ W1i,
                const float* __restrict__ in_b, __bf16* __restrict__ G) {
  __shared__ __bf16 sm[3 * BUF_ELEMS];
  // XCD-aware bijective swizzle: nwg = 128*8 = 1024, divisible by 8
  const int bid = blockIdx.x;
  const int swz = (bid & 7) * 128 + (bid >> 3);
  const long m0 = (long)(swz >> 3) * 256;
  const long n0 = (long)(swz & 7) * 256;

  f32x16 acc[4][2];
  gemm_core(X, W1i, sm, m0, n0, acc);

  const int lane = threadIdx.x & 63;
  const int w = threadIdx.x >> 6;
  const int wr = w >> 2, wc = w & 3;
  const int c31 = lane & 31;
  const int hi = lane >> 5;

  // G column for this wave's frag pair: even block j=0 (x_val), odd j=1 (res)
  const int gc = ((int)n0 >> 1) + wc * 32 + c31;
  const float bx = in_b[gc];
  const float br = in_b[1024 + gc];

#pragma unroll
  for (int i = 0; i < 4; ++i)
#pragma unroll
    for (int reg = 0; reg < 16; ++reg) {
      const int row = wr * 128 + i * 32 + (reg & 3) + 8 * (reg >> 2) + 4 * hi;
      float xv = acc[i][0][reg] + bx;
      float rs = acc[i][1][reg] + br;
      float e1 = __expf(-xv);
      float e2 = __expf(-rs);
      float g = xv * rs * __builtin_amdgcn_rcpf((1.0f + e1) * (1.0f + e2));
      G[(m0 + row) * 1024 + gc] = (__bf16)g;
    }
}

// ---------------- GEMM2: OUT = G @ W2^T + out_b (fp32) ----------------
__global__ __launch_bounds__(512, 2)
void gemm2_bias(const __bf16* __restrict__ G, const __bf16* __restrict__ W2,
                const float* __restrict__ out_b, float* __restrict__ OUT) {
  __shared__ __bf16 sm[3 * BUF_ELEMS];
  // nwg = 128*4 = 512, divisible by 8
  const int bid = blockIdx.x;
  const int swz = (bid & 7) * 64 + (bid >> 3);
  const long m0 = (long)(swz >> 2) * 256;
  const long n0 = (long)(swz & 3) * 256;

  f32x16 acc[4][2];
  gemm_core(G, W2, sm, m0, n0, acc);

  const int lane = threadIdx.x & 63;
  const int w = threadIdx.x >> 6;
  const int wr = w >> 2, wc = w & 3;
  const int c31 = lane & 31;
  const int hi = lane >> 5;

  float ob[2];
#pragma unroll
  for (int j = 0; j < 2; ++j)
    ob[j] = out_b[(int)n0 + wc * 64 + j * 32 + c31];
#pragma unroll
  for (int i = 0; i < 4; ++i)
#pragma unroll
    for (int j = 0; j < 2; ++j)
#pragma unroll
      for (int reg = 0; reg < 16; ++reg) {
        const int row = wr * 128 + i * 32 + (reg & 3) + 8 * (reg >> 2) + 4 * hi;
        const int col = (int)n0 + wc * 64 + j * 32 + c31;
        OUT[(m0 + row) * 1024 + col] = acc[i][j][reg] + ob[j];
      }
}

extern "C" void kernel_launch(void* const* d_in, const int* in_sizes, int n_in,
                              void* d_out, int out_size, void* d_ws, size_t ws_size,
                              hipStream_t stream) {
  const float* x = (const float*)d_in[0];
  const float* in_w = (const float*)d_in[1];
  const float* in_b = (const float*)d_in[2];
  const float* out_w = (const float*)d_in[3];
  const float* out_b = (const float*)d_in[4];
  // d_in[5..8] (dt_w, dt_b, A, Dp) are dead in the reference.

  char* ws = (char*)d_ws;
  __bf16* xb = (__bf16*)(ws);                       // 67108864 B
  __bf16* w1b = (__bf16*)(ws + (size_t)67108864);   //  4194304 B (blk32 interleaved)
  __bf16* w2b = (__bf16*)(ws + (size_t)71303168);   //  2097152 B
  __bf16* gb = (__bf16*)(ws + (size_t)73400320);    // 67108864 B

  cast_all<<<dim3(17920), 256, 0, stream>>>(x, xb, in_w, w1b, out_w, w2b);
  gemm1_silu<<<dim3(1024), 512, 0, stream>>>(xb, w1b, in_b, gb);
  gemm2_bias<<<dim3(512), 512, 0, stream>>>(gb, w2b, out_b, (float*)d_out);
}

// Round 15
// 252.754 us; speedup vs baseline: 1.3333x; 1.0355x over previous
//
#include <hip/hip_runtime.h>
#include <cstdint>

// MambaBlock: out = (silu(x@in_w[:1024]^T+b0) * silu(x@in_w[1024:]^T+b1)) @ out_w^T + out_b
// M = 32768, K = 1024. dt_w/dt_b/A/Dp are dead inputs.
//
// Round 15 = r11 verified core (261.0 us) + phase-split compute at 32x32:
// per K-tile, two phases {6 ds_read (k-slice) + 2 stage gloads -> barrier ->
// lgkmcnt(0)+sched_barrier -> setprio(1) -> 8 MFMA -> setprio(0)}. The
// {32x32 MFMA, 0-conflict swizzle, per-phase interleave} cell was never
// measured (r3's null was on the 16x16 core). Sync invariants identical to
// r11: tile-top WAITB(4) counted (never 0 in main loop), stage(t+2) -> buf
// (t+2)%3 after the barrier, block-uniform barrier count, same tail.
// Core: 256x256 tile, BK=32, 8 waves 2Mx4N, 3 LDS bufs (96 KiB, 1 block/CU),
// swizzle key2(row)=((row>>1)^(row>>4))&3 both sides, bijective XCD swizzle,
// shuffle-free paired-silu epilogue (blk32 W1), merged single-launch casts.
// Ledger: r3/r4 phase splits on 16x16 null; r5 32x32 +17%; r6 swizzle +4%;
// r7 fat tile spill; r8 bounds clamp spill; r10 A-cast fusion -71us; r12
// LDS-cut neutral (register-pinned occupancy); r13 B-direct -71us.

typedef __bf16 bf16x8 __attribute__((ext_vector_type(8)));
typedef float f32x16 __attribute__((ext_vector_type(16)));

#define KD 1024
#define BUF_ELEMS 16384  // (256*32 A + 256*32 B) elems per buffer

__device__ __forceinline__ void gload_lds16(const void* g, void* lds_u) {
  __builtin_amdgcn_global_load_lds(
      (__attribute__((address_space(1))) void*)(uintptr_t)g,
      (__attribute__((address_space(3))) void*)(uint32_t)(uintptr_t)lds_u,
      16, 0, 0);
}

#define WAITB(N) do { \
  asm volatile("s_waitcnt vmcnt(" #N ")" ::: "memory"); \
  asm volatile("s_barrier" ::: "memory"); } while (0)

#define PH_GATE() do { \
  __builtin_amdgcn_s_barrier(); \
  asm volatile("s_waitcnt lgkmcnt(0)" ::: "memory"); \
  __builtin_amdgcn_sched_barrier(0); \
  __builtin_amdgcn_s_setprio(1); } while (0)

// ---------------- merged cast kernel (single launch) ----------------
// blocks [0, 16384): x -> xb; [16384, 17408): in_w -> w1b (blk32 interleave);
// [17408, 17920): out_w -> w2b
__global__ void cast_all(const float* __restrict__ x, __bf16* __restrict__ xb,
                         const float* __restrict__ in_w, __bf16* __restrict__ w1b,
                         const float* __restrict__ out_w, __bf16* __restrict__ w2b) {
  const int b = blockIdx.x;
  if (b < 16384) {
    int i = b * 256 + threadIdx.x;  // < 4194304 = 33554432/8
    const float4* p = (const float4*)x;
    float4 v0 = p[2 * i];
    float4 v1 = p[2 * i + 1];
    bf16x8 o;
    o[0] = (__bf16)v0.x; o[1] = (__bf16)v0.y; o[2] = (__bf16)v0.z; o[3] = (__bf16)v0.w;
    o[4] = (__bf16)v1.x; o[5] = (__bf16)v1.y; o[6] = (__bf16)v1.z; o[7] = (__bf16)v1.w;
    ((bf16x8*)xb)[i] = o;
  } else if (b < 17408) {
    // W1'' 32-row block interleave: out-row r, blk=r>>5, t=r&31:
    //   src row = (blk&1)*1024 + (blk>>1)*32 + t
    int i = (b - 16384) * 256 + threadIdx.x;  // 2048*128 threads
    int orow = i >> 7;
    int chunk = i & 127;
    int bb = orow >> 5, t = orow & 31;
    int srow = (bb & 1) * 1024 + (bb >> 1) * 32 + t;
    const float4* p = (const float4*)(in_w + ((size_t)srow << 10) + (chunk << 3));
    float4 v0 = p[0], v1 = p[1];
    bf16x8 o;
    o[0] = (__bf16)v0.x; o[1] = (__bf16)v0.y; o[2] = (__bf16)v0.z; o[3] = (__bf16)v0.w;
    o[4] = (__bf16)v1.x; o[5] = (__bf16)v1.y; o[6] = (__bf16)v1.z; o[7] = (__bf16)v1.w;
    *(bf16x8*)(w1b + ((size_t)orow << 10) + (chunk << 3)) = o;
  } else {
    int i = (b - 17408) * 256 + threadIdx.x;  // < 131072 = 1048576/8
    const float4* p = (const float4*)out_w;
    float4 v0 = p[2 * i];
    float4 v1 = p[2 * i + 1];
    bf16x8 o;
    o[0] = (__bf16)v0.x; o[1] = (__bf16)v0.y; o[2] = (__bf16)v0.z; o[3] = (__bf16)v0.w;
    o[4] = (__bf16)v1.x; o[5] = (__bf16)v1.y; o[6] = (__bf16)v1.z; o[7] = (__bf16)v1.w;
    ((bf16x8*)w2b)[i] = o;
  }
}

// ---------------- GEMM core ----------------
// Phase-split compute of one K-tile from buffer BUF, staging tile t+2's
// A-half (phase 1) and B-half (phase 2) into buffer SBUF when DO_STAGE.
// k-slice 0 reads chunk o0 (i even) / o1 (i odd); k-slice 1 swapped.
template <int BUF, int SBUF, bool DO_STAGE>
__device__ __forceinline__ void compute_tile(const __bf16* sm,
                                             int aRow, int bRow,
                                             int o0, int o1,
                                             const __bf16*& pa, const __bf16*& pb,
                                             __bf16* smw,
                                             f32x16 (&acc)[4][2]) {
  const __bf16* base = sm + BUF * BUF_ELEMS;
  __bf16* d = smw + SBUF * BUF_ELEMS;
  // ---- phase 1: k-slice 0 (6 ds_read) + stage A pair ----
  bf16x8 a0[4], b0[2];
  b0[0] = *(const bf16x8*)(base + bRow + o0);
  b0[1] = *(const bf16x8*)(base + bRow + 1024 + o1);
#pragma unroll
  for (int i = 0; i < 4; ++i)
    a0[i] = *(const bf16x8*)(base + aRow + i * 1024 + ((i & 1) ? o1 : o0));
  if (DO_STAGE) {
    gload_lds16(pa, d);
    gload_lds16(pa + 128 * KD, d + 4096);
    pa += 32;
  }
  PH_GATE();
#pragma unroll
  for (int i = 0; i < 4; ++i)
#pragma unroll
    for (int j = 0; j < 2; ++j)
      acc[i][j] = __builtin_amdgcn_mfma_f32_32x32x16_bf16(a0[i], b0[j], acc[i][j], 0, 0, 0);
  __builtin_amdgcn_s_setprio(0);
  // ---- phase 2: k-slice 1 (6 ds_read) + stage B pair ----
  bf16x8 a1[4], b1[2];
  b1[0] = *(const bf16x8*)(base + bRow + o1);
  b1[1] = *(const bf16x8*)(base + bRow + 1024 + o0);
#pragma unroll
  for (int i = 0; i < 4; ++i)
    a1[i] = *(const bf16x8*)(base + aRow + i * 1024 + ((i & 1) ? o0 : o1));
  if (DO_STAGE) {
    gload_lds16(pb, d + 8192);
    gload_lds16(pb + 128 * KD, d + 12288);
    pb += 32;
  }
  PH_GATE();
#pragma unroll
  for (int i = 0; i < 4; ++i)
#pragma unroll
    for (int j = 0; j < 2; ++j)
      acc[i][j] = __builtin_amdgcn_mfma_f32_32x32x16_bf16(a1[i], b1[j], acc[i][j], 0, 0, 0);
  __builtin_amdgcn_s_setprio(0);
}

// Prologue staging of one full K-tile (4 gloads), as in r11.
template <int BUF>
__device__ __forceinline__ void stage_tile(const __bf16*& pa, const __bf16*& pb,
                                           __bf16* smw) {
  __bf16* d = smw + BUF * BUF_ELEMS;
  gload_lds16(pa, d);
  gload_lds16(pa + 128 * KD, d + 4096);
  gload_lds16(pb, d + 8192);
  gload_lds16(pb + 128 * KD, d + 12288);
  pa += 32;
  pb += 32;
}

// Fills acc for the 256x256 tile at (m0, n0). A:[M][1024], B:[Nrows][1024].
__device__ __forceinline__ void gemm_core(const __bf16* __restrict__ A,
                                          const __bf16* __restrict__ B,
                                          __bf16* sm, long m0, long n0,
                                          f32x16 (&acc)[4][2]) {
  const int t = threadIdx.x;
  const int w = t >> 6;
  const int lane = t & 63;
  const int c31 = lane & 31;
  const int hi = lane >> 5;
  const int wr = w >> 2;  // 0..1 (M)
  const int wc = w & 3;   // 0..3 (N)

  // staging source: lane l covers LDS row w*16+(l>>2), phys slot l&3, which
  // must hold logical chunk (l&3) ^ key2(row); key2 = ((l>>3)&3) ^ (w&3).
  const int l = lane;
  const int stg_row = w * 16 + (l >> 2);
  const int stg_col = ((l & 3) ^ ((l >> 3) & 3) ^ (w & 3)) << 3;
  const __bf16* pa = A + (m0 + stg_row) * KD + stg_col;
  const __bf16* pb = B + (n0 + stg_row) * KD + stg_col;
  __bf16* smw = sm + w * 512;  // wave-uniform LDS base (1024B per wave-instr)

  // fragment read offsets. key_base = ((c31>>1)&3) ^ ((c31>>4)&1); frag idx
  // parity flips key by 2 (row bit 5 via r>>4). o1 = o0 ^ 16 elems.
  const int key_base = ((c31 >> 1) & 3) ^ ((c31 >> 4) & 1);
  const int o0 = (hi ^ key_base) << 3;
  const int o1 = o0 ^ 16;
  const int aRow = (wr * 128 + c31) * 32;          // + i*1024
  const int bRow = 8192 + (wc * 64 + c31) * 32;    // + j*1024

#pragma unroll
  for (int i = 0; i < 4; ++i)
#pragma unroll
    for (int j = 0; j < 2; ++j)
      acc[i][j] = (f32x16){0.f, 0.f, 0.f, 0.f, 0.f, 0.f, 0.f, 0.f,
                           0.f, 0.f, 0.f, 0.f, 0.f, 0.f, 0.f, 0.f};

  // prologue: stage tiles 0,1 (outstanding = 8)
  stage_tile<0>(pa, pb, smw);
  stage_tile<1>(pa, pb, smw);

  // tiles 0..29: tile-top WAITB(4) retires stage(t); phases stage tile t+2
  // into buf (t+2)%3 (A pair in ph1, B pair in ph2) -> outstanding back to 8.
  for (int it = 0; it < 10; ++it) {
    WAITB(4);
    compute_tile<0, 2, true>(sm, aRow, bRow, o0, o1, pa, pb, smw, acc);
    WAITB(4);
    compute_tile<1, 0, true>(sm, aRow, bRow, o0, o1, pa, pb, smw, acc);
    WAITB(4);
    compute_tile<2, 1, true>(sm, aRow, bRow, o0, o1, pa, pb, smw, acc);
  }
  // tail: tiles 30 (buf0), 31 (buf1), no staging
  WAITB(4);
  compute_tile<0, 2, false>(sm, aRow, bRow, o0, o1, pa, pb, smw, acc);
  WAITB(0);
  compute_tile<1, 2, false>(sm, aRow, bRow, o0, o1, pa, pb, smw, acc);
}

// ---------------- GEMM1: Y = X @ W1''^T, paired-silu epilogue -> G bf16 -----
__global__ __launch_bounds__(512, 2)
void gemm1_silu(const __bf16* __restrict__ X, const __bf16* __restrict__ W1i,
                const float* __restrict__ in_b, __bf16* __restrict__ G) {
  __shared__ __bf16 sm[3 * BUF_ELEMS];
  // XCD-aware bijective swizzle: nwg = 128*8 = 1024, divisible by 8
  const int bid = blockIdx.x;
  const int swz = (bid & 7) * 128 + (bid >> 3);
  const long m0 = (long)(swz >> 3) * 256;
  const long n0 = (long)(swz & 7) * 256;

  f32x16 acc[4][2];
  gemm_core(X, W1i, sm, m0, n0, acc);

  const int lane = threadIdx.x & 63;
  const int w = threadIdx.x >> 6;
  const int wr = w >> 2, wc = w & 3;
  const int c31 = lane & 31;
  const int hi = lane >> 5;

  // G column for this wave's frag pair: even block j=0 (x_val), odd j=1 (res)
  const int gc = ((int)n0 >> 1) + wc * 32 + c31;
  const float bx = in_b[gc];
  const float br = in_b[1024 + gc];

#pragma unroll
  for (int i = 0; i < 4; ++i)
#pragma unroll
    for (int reg = 0; reg < 16; ++reg) {
      const int row = wr * 128 + i * 32 + (reg & 3) + 8 * (reg >> 2) + 4 * hi;
      float xv = acc[i][0][reg] + bx;
      float rs = acc[i][1][reg] + br;
      float e1 = __expf(-xv);
      float e2 = __expf(-rs);
      float g = xv * rs * __builtin_amdgcn_rcpf((1.0f + e1) * (1.0f + e2));
      G[(m0 + row) * 1024 + gc] = (__bf16)g;
    }
}

// ---------------- GEMM2: OUT = G @ W2^T + out_b (fp32) ----------------
__global__ __launch_bounds__(512, 2)
void gemm2_bias(const __bf16* __restrict__ G, const __bf16* __restrict__ W2,
                const float* __restrict__ out_b, float* __restrict__ OUT) {
  __shared__ __bf16 sm[3 * BUF_ELEMS];
  // nwg = 128*4 = 512, divisible by 8
  const int bid = blockIdx.x;
  const int swz = (bid & 7) * 64 + (bid >> 3);
  const long m0 = (long)(swz >> 2) * 256;
  const long n0 = (long)(swz & 3) * 256;

  f32x16 acc[4][2];
  gemm_core(G, W2, sm, m0, n0, acc);

  const int lane = threadIdx.x & 63;
  const int w = threadIdx.x >> 6;
  const int wr = w >> 2, wc = w & 3;
  const int c31 = lane & 31;
  const int hi = lane >> 5;

  float ob[2];
#pragma unroll
  for (int j = 0; j < 2; ++j)
    ob[j] = out_b[(int)n0 + wc * 64 + j * 32 + c31];
#pragma unroll
  for (int i = 0; i < 4; ++i)
#pragma unroll
    for (int j = 0; j < 2; ++j)
#pragma unroll
      for (int reg = 0; reg < 16; ++reg) {
        const int row = wr * 128 + i * 32 + (reg & 3) + 8 * (reg >> 2) + 4 * hi;
        const int col = (int)n0 + wc * 64 + j * 32 + c31;
        OUT[(m0 + row) * 1024 + col] = acc[i][j][reg] + ob[j];
      }
}

extern "C" void kernel_launch(void* const* d_in, const int* in_sizes, int n_in,
                              void* d_out, int out_size, void* d_ws, size_t ws_size,
                              hipStream_t stream) {
  const float* x = (const float*)d_in[0];
  const float* in_w = (const float*)d_in[1];
  const float* in_b = (const float*)d_in[2];
  const float* out_w = (const float*)d_in[3];
  const float* out_b = (const float*)d_in[4];
  // d_in[5..8] (dt_w, dt_b, A, Dp) are dead in the reference.

  char* ws = (char*)d_ws;
  __bf16* xb = (__bf16*)(ws);                       // 67108864 B
  __bf16* w1b = (__bf16*)(ws + (size_t)67108864);   //  4194304 B (blk32 interleaved)
  __bf16* w2b = (__bf16*)(ws + (size_t)71303168);   //  2097152 B
  __bf16* gb = (__bf16*)(ws + (size_t)73400320);    // 67108864 B

  cast_all<<<dim3(17920), 256, 0, stream>>>(x, xb, in_w, w1b, out_w, w2b);
  gemm1_silu<<<dim3(1024), 512, 0, stream>>>(xb, w1b, in_b, gb);
  gemm2_bias<<<dim3(512), 512, 0, stream>>>(gb, w2b, out_b, (float*)d_out);
}